// Round 6
// baseline (346.367 us; speedup 1.0000x reference)
//
#include <hip/hip_runtime.h>

#define TT 512
#define FF 8
#define CC 16
#define HH 10
#define G4 40

__device__ __forceinline__ float rl(float v, int k){
    return __int_as_float(__builtin_amdgcn_readlane(__float_as_int(v), k));
}
__device__ __forceinline__ float sigf(float z){
    return __builtin_amdgcn_rcpf(1.f + __expf(-z));
}
__device__ __forceinline__ float tanh_f(float z){
    return 1.f - 2.f * __builtin_amdgcn_rcpf(1.f + __expf(2.f * z));
}

// ======================= R5 fallback kernel (unchanged) =======================
#define CONV_Y(Y) do{                                                                              \
    float a0 = cb, a1 = 0.f;                                                                       \
    a0 = fmaf(w0a.x, cw[0],  a0); a1 = fmaf(w1a.x, cw[1],  a1); a0 = fmaf(w2a.x, cw[2],  a0);      \
    a1 = fmaf(w0a.y, cw[3],  a1); a0 = fmaf(w1a.y, cw[4],  a0); a1 = fmaf(w2a.y, cw[5],  a1);      \
    a0 = fmaf(w0a.z, cw[6],  a0); a1 = fmaf(w1a.z, cw[7],  a1); a0 = fmaf(w2a.z, cw[8],  a0);      \
    a1 = fmaf(w0a.w, cw[9],  a1); a0 = fmaf(w1a.w, cw[10], a0); a1 = fmaf(w2a.w, cw[11], a1);      \
    a0 = fmaf(w0b.x, cw[12], a0); a1 = fmaf(w1b.x, cw[13], a1); a0 = fmaf(w2b.x, cw[14], a0);      \
    a1 = fmaf(w0b.y, cw[15], a1); a0 = fmaf(w1b.y, cw[16], a0); a1 = fmaf(w2b.y, cw[17], a1);      \
    a0 = fmaf(w0b.z, cw[18], a0); a1 = fmaf(w1b.z, cw[19], a1); a0 = fmaf(w2b.z, cw[20], a0);      \
    a1 = fmaf(w0b.w, cw[21], a1); a0 = fmaf(w1b.w, cw[22], a0); a1 = fmaf(w2b.w, cw[23], a1);      \
    Y = fmaxf(a0 + a1, 0.f);                                                                       \
}while(0)

#define H1BCAST                                                                                    \
    const float hs0=rl(h1,0), hs1=rl(h1,1), hs2=rl(h1,2), hs3=rl(h1,3), hs4=rl(h1,4),              \
                hs5=rl(h1,5), hs6=rl(h1,6), hs7=rl(h1,7), hs8=rl(h1,8), hs9=rl(h1,9);

#define LAYER2 do{                                                                                 \
    float d0 = b2, d1 = 0.f;                                                                       \
    d0 = fmaf(hs0, wih2[0], d0);  d1 = fmaf(hs1, wih2[1], d1);                                     \
    d0 = fmaf(hs2, wih2[2], d0);  d1 = fmaf(hs3, wih2[3], d1);                                     \
    d0 = fmaf(hs4, wih2[4], d0);  d1 = fmaf(hs5, wih2[5], d1);                                     \
    d0 = fmaf(hs6, wih2[6], d0);  d1 = fmaf(hs7, wih2[7], d1);                                     \
    d0 = fmaf(hs8, wih2[8], d0);  d1 = fmaf(hs9, wih2[9], d1);                                     \
    d0 = fmaf(rl(h2,0), whh2[0], d0);  d1 = fmaf(rl(h2,1), whh2[1], d1);                           \
    d0 = fmaf(rl(h2,2), whh2[2], d0);  d1 = fmaf(rl(h2,3), whh2[3], d1);                           \
    d0 = fmaf(rl(h2,4), whh2[4], d0);  d1 = fmaf(rl(h2,5), whh2[5], d1);                           \
    d0 = fmaf(rl(h2,6), whh2[6], d0);  d1 = fmaf(rl(h2,7), whh2[7], d1);                           \
    d0 = fmaf(rl(h2,8), whh2[8], d0);  d1 = fmaf(rl(h2,9), whh2[9], d1);                           \
    const float g2  = d0 + d1;                                                                     \
    const float z2  = isG ? (g2 + g2) : g2;                                                        \
    const float sg2 = sigf(z2);                                                                    \
    const float act2 = isG ? fmaf(2.f, sg2, -1.f) : sg2;                                           \
    const float ai2 = __shfl(act2, u,      64);                                                    \
    const float af2 = __shfl(act2, u + 10, 64);                                                    \
    const float ag2 = __shfl(act2, u + 20, 64);                                                    \
    const float ao2 = __shfl(act2, u + 30, 64);                                                    \
    c2 = fmaf(af2, c2, ai2 * ag2);                                                                 \
    h2 = ao2 * tanh_f(c2);                                                                         \
}while(0)

#define LAYER1(YV) do{                                                                             \
    float s0 = b1, s1 = 0.f;                                                                       \
    s0 = fmaf(rl(YV,0),  wih1[0],  s0);  s1 = fmaf(rl(YV,1),  wih1[1],  s1);                       \
    s0 = fmaf(rl(YV,2),  wih1[2],  s0);  s1 = fmaf(rl(YV,3),  wih1[3],  s1);                       \
    s0 = fmaf(rl(YV,4),  wih1[4],  s0);  s1 = fmaf(rl(YV,5),  wih1[5],  s1);                       \
    s0 = fmaf(rl(YV,6),  wih1[6],  s0);  s1 = fmaf(rl(YV,7),  wih1[7],  s1);                       \
    s0 = fmaf(rl(YV,8),  wih1[8],  s0);  s1 = fmaf(rl(YV,9),  wih1[9],  s1);                       \
    s0 = fmaf(rl(YV,10), wih1[10], s0);  s1 = fmaf(rl(YV,11), wih1[11], s1);                       \
    s0 = fmaf(rl(YV,12), wih1[12], s0);  s1 = fmaf(rl(YV,13), wih1[13], s1);                       \
    s0 = fmaf(rl(YV,14), wih1[14], s0);  s1 = fmaf(rl(YV,15), wih1[15], s1);                       \
    s0 = fmaf(hs0, whh1[0], s0);  s1 = fmaf(hs1, whh1[1], s1);                                     \
    s0 = fmaf(hs2, whh1[2], s0);  s1 = fmaf(hs3, whh1[3], s1);                                     \
    s0 = fmaf(hs4, whh1[4], s0);  s1 = fmaf(hs5, whh1[5], s1);                                     \
    s0 = fmaf(hs6, whh1[6], s0);  s1 = fmaf(hs7, whh1[7], s1);                                     \
    s0 = fmaf(hs8, whh1[8], s0);  s1 = fmaf(hs9, whh1[9], s1);                                     \
    const float g1  = s0 + s1;                                                                     \
    const float z1  = isG ? (g1 + g1) : g1;                                                        \
    const float sg1 = sigf(z1);                                                                    \
    const float act1 = isG ? fmaf(2.f, sg1, -1.f) : sg1;                                           \
    const float ai1 = __shfl(act1, u,      64);                                                    \
    const float af1 = __shfl(act1, u + 10, 64);                                                    \
    const float ag1 = __shfl(act1, u + 20, 64);                                                    \
    const float ao1 = __shfl(act1, u + 30, 64);                                                    \
    c1 = fmaf(af1, c1, ai1 * ag1);                                                                 \
    h1n = ao1 * tanh_f(c1);                                                                        \
}while(0)

__global__ __launch_bounds__(64, 2)
void lstm_fused(const float* __restrict__ x,
                const float* __restrict__ conv_w, const float* __restrict__ conv_b,
                const float* __restrict__ w_ih1,  const float* __restrict__ w_hh1,
                const float* __restrict__ b_ih1,  const float* __restrict__ b_hh1,
                const float* __restrict__ w_ih2,  const float* __restrict__ w_hh2,
                const float* __restrict__ b_ih2,  const float* __restrict__ b_hh2,
                const float* __restrict__ lin_w,  const float* __restrict__ lin_b,
                float* __restrict__ out)
{
    const int lane  = threadIdx.x;
    const int batch = blockIdx.x;
    const int grow  = (lane < G4) ? lane : (G4-1);
    const int q     = grow / 10;
    const int u     = grow - q * 10;
    const int ch    = lane & 15;
    const bool isG  = (q == 2);

    float cw[24];
    #pragma unroll
    for (int m = 0; m < 24; ++m) cw[m] = conv_w[ch*24 + m];
    const float cb = conv_b[ch];

    float wih1[CC], whh1[HH], wih2[HH], whh2[HH];
    #pragma unroll
    for (int k = 0; k < CC; ++k) wih1[k] = w_ih1[grow*CC + k];
    #pragma unroll
    for (int k = 0; k < HH; ++k){
        whh1[k] = w_hh1[grow*HH + k];
        wih2[k] = w_ih2[grow*HH + k];
        whh2[k] = w_hh2[grow*HH + k];
    }
    const float b1 = b_ih1[grow] + b_hh1[grow];
    const float b2 = b_ih2[grow] + b_hh2[grow];

    const float* xb = x + (size_t)batch * (TT*FF);

    float h1 = 0.f, c1 = 0.f, h2 = 0.f, c2 = 0.f, h1n;

    float4 w0a = make_float4(0.f,0.f,0.f,0.f), w0b = w0a;
    float4 w1a = *(const float4*)(xb + 0);
    float4 w1b = *(const float4*)(xb + 4);
    float4 w2a = *(const float4*)(xb + 8);
    float4 w2b = *(const float4*)(xb + 12);

    {
        float y0; CONV_Y(y0);
        H1BCAST;
        LAYER1(y0);
        h1 = h1n;
    }
    w0a = w1a; w0b = w1b; w1a = w2a; w1b = w2b;
    w2a = *(const float4*)(xb + 16);
    w2b = *(const float4*)(xb + 20);

    #pragma unroll 3
    for (int t = 1; t < TT; ++t){
        float4 nxa = make_float4(0.f,0.f,0.f,0.f), nxb = nxa;
        if (t + 2 < TT){
            const float* p = xb + (t+2)*FF;
            nxa = *(const float4*)p;
            nxb = *(const float4*)(p + 4);
        }
        float y; CONV_Y(y);
        {
            H1BCAST;
            LAYER2;
            LAYER1(y);
        }
        h1 = h1n;
        w0a = w1a; w0b = w1b; w1a = w2a; w1b = w2b; w2a = nxa; w2b = nxb;
    }
    {
        H1BCAST;
        LAYER2;
    }

    float part = (lane < HH) ? h2 * lin_w[lane] : 0.f;
    #pragma unroll
    for (int off = 8; off > 0; off >>= 1) part += __shfl_xor(part, off, 16);
    if (lane == 0) out[batch] = sigf(part + lin_b[0]);
}

// ======================= Kernel A: parallel conv + W_ih1.y ====================
// One block (256 thr) per batch. xg[b][t][g] = b_ih1[g]+b_hh1[g] + sum_k W_ih1[g][k]*y[b][t][k]
__global__ __launch_bounds__(256)
void precompute_xg(const float* __restrict__ x,
                   const float* __restrict__ conv_w, const float* __restrict__ conv_b,
                   const float* __restrict__ w_ih1,  const float* __restrict__ b_ih1,
                   const float* __restrict__ b_hh1,
                   float* __restrict__ xg)
{
    __shared__ __align__(16) float xs[TT][FF];        // 16 KB
    __shared__ __align__(16) float ys[TT][CC];        // 32 KB
    __shared__ float wl[G4][CC + 1];                  // padded vs bank conflicts
    __shared__ float bl[G4];

    const int tid = threadIdx.x;
    const int b   = blockIdx.x;
    const float* xb = x + (size_t)b * (TT*FF);

    for (int i = tid; i < TT*FF/4; i += 256)
        ((float4*)xs)[i] = ((const float4*)xb)[i];
    for (int i = tid; i < G4*CC; i += 256){
        int g = i >> 4, k = i & 15;
        wl[g][k] = w_ih1[g*CC + k];
    }
    if (tid < G4) bl[tid] = b_ih1[tid] + b_hh1[tid];
    __syncthreads();

    // conv+relu: thread = (seg, ch); 32 consecutive t each, sliding window
    {
        const int ch  = tid & 15;
        const int seg = tid >> 4;          // 0..15
        float cw[24];
        #pragma unroll
        for (int m = 0; m < 24; ++m) cw[m] = conv_w[ch*24 + m];
        const float cb = conv_b[ch];
        const int t0 = seg * 32;
        float4 w0a, w0b, w1a, w1b, w2a, w2b;
        if (t0 == 0){ w0a = make_float4(0.f,0.f,0.f,0.f); w0b = w0a; }
        else        { w0a = *(const float4*)&xs[t0-1][0]; w0b = *(const float4*)&xs[t0-1][4]; }
        w1a = *(const float4*)&xs[t0][0]; w1b = *(const float4*)&xs[t0][4];
        #pragma unroll 4
        for (int i = 0; i < 32; ++i){
            const int t = t0 + i;
            if (t + 1 < TT){ w2a = *(const float4*)&xs[t+1][0]; w2b = *(const float4*)&xs[t+1][4]; }
            else           { w2a = make_float4(0.f,0.f,0.f,0.f); w2b = w2a; }
            float y; CONV_Y(y);
            ys[t][ch] = y;
            w0a = w1a; w0b = w1b; w1a = w2a; w1b = w2b;
        }
    }
    __syncthreads();

    // xg: 512*40 outputs, 80 per thread, coalesced stores
    {
        int t = tid / G4;
        int g = tid - t * G4;
        float* xgb = xg + (size_t)b * (TT*G4);
        #pragma unroll 4
        for (int i = 0; i < 80; ++i){
            const float4 y0 = *(const float4*)&ys[t][0];
            const float4 y1 = *(const float4*)&ys[t][4];
            const float4 y2 = *(const float4*)&ys[t][8];
            const float4 y3 = *(const float4*)&ys[t][12];
            float s0 = bl[g], s1 = 0.f;
            s0 = fmaf(y0.x, wl[g][0],  s0);  s1 = fmaf(y0.y, wl[g][1],  s1);
            s0 = fmaf(y0.z, wl[g][2],  s0);  s1 = fmaf(y0.w, wl[g][3],  s1);
            s0 = fmaf(y1.x, wl[g][4],  s0);  s1 = fmaf(y1.y, wl[g][5],  s1);
            s0 = fmaf(y1.z, wl[g][6],  s0);  s1 = fmaf(y1.w, wl[g][7],  s1);
            s0 = fmaf(y2.x, wl[g][8],  s0);  s1 = fmaf(y2.y, wl[g][9],  s1);
            s0 = fmaf(y2.z, wl[g][10], s0);  s1 = fmaf(y2.w, wl[g][11], s1);
            s0 = fmaf(y3.x, wl[g][12], s0);  s1 = fmaf(y3.y, wl[g][13], s1);
            s0 = fmaf(y3.z, wl[g][14], s0);  s1 = fmaf(y3.w, wl[g][15], s1);
            xgb[t*G4 + g] = s0 + s1;
            t += 6; g += 16; if (g >= G4){ g -= G4; ++t; }   // advance by 256
        }
    }
}

// ======================= Kernel B: serial recurrence only =====================
#define LAYER2B do{                                                               \
    float d0 = b2, d1 = 0.f;                                                      \
    d0 = fmaf(hs0, wih2[0], d0);  d1 = fmaf(hs1, wih2[1], d1);                    \
    d0 = fmaf(hs2, wih2[2], d0);  d1 = fmaf(hs3, wih2[3], d1);                    \
    d0 = fmaf(hs4, wih2[4], d0);  d1 = fmaf(hs5, wih2[5], d1);                    \
    d0 = fmaf(hs6, wih2[6], d0);  d1 = fmaf(hs7, wih2[7], d1);                    \
    d0 = fmaf(hs8, wih2[8], d0);  d1 = fmaf(hs9, wih2[9], d1);                    \
    d0 = fmaf(rl(h2,0), whh2[0], d0);  d1 = fmaf(rl(h2,1), whh2[1], d1);          \
    d0 = fmaf(rl(h2,2), whh2[2], d0);  d1 = fmaf(rl(h2,3), whh2[3], d1);          \
    d0 = fmaf(rl(h2,4), whh2[4], d0);  d1 = fmaf(rl(h2,5), whh2[5], d1);          \
    d0 = fmaf(rl(h2,6), whh2[6], d0);  d1 = fmaf(rl(h2,7), whh2[7], d1);          \
    d0 = fmaf(rl(h2,8), whh2[8], d0);  d1 = fmaf(rl(h2,9), whh2[9], d1);          \
    const float g2  = d0 + d1;                                                    \
    const float sg2 = sigf(g2 * zM);                                              \
    const float act2 = fmaf(aA, sg2, aB);                                         \
    const float ai2 = __shfl(act2, u,      64);                                   \
    const float af2 = __shfl(act2, u + 10, 64);                                   \
    const float ag2 = __shfl(act2, u + 20, 64);                                   \
    const float ao2 = __shfl(act2, u + 30, 64);                                   \
    c2 = fmaf(af2, c2, ai2 * ag2);                                                \
    h2 = ao2 * tanh_f(c2);                                                        \
}while(0)

#define LAYER1B(XGV) do{                                                          \
    float s0 = (XGV), s1 = 0.f;                                                   \
    s0 = fmaf(hs0, whh1[0], s0);  s1 = fmaf(hs1, whh1[1], s1);                    \
    s0 = fmaf(hs2, whh1[2], s0);  s1 = fmaf(hs3, whh1[3], s1);                    \
    s0 = fmaf(hs4, whh1[4], s0);  s1 = fmaf(hs5, whh1[5], s1);                    \
    s0 = fmaf(hs6, whh1[6], s0);  s1 = fmaf(hs7, whh1[7], s1);                    \
    s0 = fmaf(hs8, whh1[8], s0);  s1 = fmaf(hs9, whh1[9], s1);                    \
    const float g1  = s0 + s1;                                                    \
    const float sg1 = sigf(g1 * zM);                                              \
    const float act1 = fmaf(aA, sg1, aB);                                         \
    const float ai1 = __shfl(act1, u,      64);                                   \
    const float af1 = __shfl(act1, u + 10, 64);                                   \
    const float ag1 = __shfl(act1, u + 20, 64);                                   \
    const float ao1 = __shfl(act1, u + 30, 64);                                   \
    c1 = fmaf(af1, c1, ai1 * ag1);                                                \
    h1n = ao1 * tanh_f(c1);                                                       \
}while(0)

__global__ __launch_bounds__(64, 2)
void lstm_seq(const float* __restrict__ xg,
              const float* __restrict__ w_hh1,
              const float* __restrict__ w_ih2,  const float* __restrict__ w_hh2,
              const float* __restrict__ b_ih2,  const float* __restrict__ b_hh2,
              const float* __restrict__ lin_w,  const float* __restrict__ lin_b,
              float* __restrict__ out)
{
    const int lane  = threadIdx.x;
    const int batch = blockIdx.x;
    const int grow  = (lane < G4) ? lane : (G4-1);
    const int q     = grow / 10;
    const int u     = grow - q * 10;
    const bool isG  = (q == 2);
    const float zM = isG ? 2.f : 1.f;     // pre-activation scale (tanh = 2*sig(2z)-1)
    const float aA = isG ? 2.f : 1.f;
    const float aB = isG ? -1.f : 0.f;

    float whh1[HH], wih2[HH], whh2[HH];
    #pragma unroll
    for (int k = 0; k < HH; ++k){
        whh1[k] = w_hh1[grow*HH + k];
        wih2[k] = w_ih2[grow*HH + k];
        whh2[k] = w_hh2[grow*HH + k];
    }
    const float b2 = b_ih2[grow] + b_hh2[grow];

    const float* xp = xg + (size_t)batch * (TT*G4) + grow;

    float h1 = 0.f, c1 = 0.f, h2 = 0.f, c2 = 0.f, h1n;

    float xgv = xp[0];
    {   // t=0: layer1 only (h1 = 0)
        H1BCAST;
        LAYER1B(xgv);
        h1 = h1n;
    }
    float xgnext = xp[G4];    // t=1

    #pragma unroll 2
    for (int t = 1; t < TT; ++t){
        const float xgcur = xgnext;
        const int tn = (t + 1 < TT) ? (t + 1) : (TT - 1);
        xgnext = xp[(size_t)tn * G4];     // prefetch next step
        H1BCAST;
        LAYER2B;                           // h2(t-1) — chain A
        LAYER1B(xgcur);                    // h1(t)   — chain B
        h1 = h1n;
    }
    { H1BCAST; LAYER2B; }                  // t = TT-1

    float part = (lane < HH) ? h2 * lin_w[lane] : 0.f;
    #pragma unroll
    for (int off = 8; off > 0; off >>= 1) part += __shfl_xor(part, off, 16);
    if (lane == 0) out[batch] = sigf(part + lin_b[0]);
}

extern "C" void kernel_launch(void* const* d_in, const int* in_sizes, int n_in,
                              void* d_out, int out_size, void* d_ws, size_t ws_size,
                              hipStream_t stream) {
    const float* x      = (const float*)d_in[0];
    const float* conv_w = (const float*)d_in[1];
    const float* conv_b = (const float*)d_in[2];
    const float* w_ih1  = (const float*)d_in[3];
    const float* w_hh1  = (const float*)d_in[4];
    const float* b_ih1  = (const float*)d_in[5];
    const float* b_hh1  = (const float*)d_in[6];
    const float* w_ih2  = (const float*)d_in[7];
    const float* w_hh2  = (const float*)d_in[8];
    const float* b_ih2  = (const float*)d_in[9];
    const float* b_hh2  = (const float*)d_in[10];
    const float* lin_w  = (const float*)d_in[11];
    const float* lin_b  = (const float*)d_in[12];
    float* out = (float*)d_out;

    const int NB = 2048;
    const size_t XG_BYTES = (size_t)NB * TT * G4 * sizeof(float);   // 167,772,160

    if (ws_size >= XG_BYTES){
        float* xgws = (float*)d_ws;
        precompute_xg<<<dim3(NB), dim3(256), 0, stream>>>(
            x, conv_w, conv_b, w_ih1, b_ih1, b_hh1, xgws);
        lstm_seq<<<dim3(NB), dim3(64), 0, stream>>>(
            xgws, w_hh1, w_ih2, w_hh2, b_ih2, b_hh2, lin_w, lin_b, out);
    } else {
        // fallback: fused single kernel (R5)
        lstm_fused<<<dim3(NB), dim3(64), 0, stream>>>(
            x, conv_w, conv_b, w_ih1, w_hh1, b_ih1, b_hh1,
            w_ih2, w_hh2, b_ih2, b_hh2, lin_w, lin_b, out);
    }
}

// Round 7
// 271.018 us; speedup vs baseline: 1.2780x; 1.2780x over previous
//
#include <hip/hip_runtime.h>

#define TT 512
#define FF 8
#define CC 16
#define HH 10
#define G4 40

__device__ __forceinline__ float rl(float v, int k){
    return __int_as_float(__builtin_amdgcn_readlane(__float_as_int(v), k));
}
__device__ __forceinline__ float sigf(float z){
    return __builtin_amdgcn_rcpf(1.f + __expf(-z));
}
__device__ __forceinline__ float tanh_f(float z){
    return 1.f - 2.f * __builtin_amdgcn_rcpf(1.f + __expf(2.f * z));
}
// Pin a value into a VGPR: asm output is opaque -> compiler must keep it live
// in a register instead of demoting to scratch / re-loading from memory.
#define PIN(v) asm volatile("" : "+v"(v))

#define CONV_Y(Y) do{                                                                              \
    float a0 = cb, a1 = 0.f;                                                                       \
    a0 = fmaf(w0a.x, cw0,  a0); a1 = fmaf(w1a.x, cw1,  a1); a0 = fmaf(w2a.x, cw2,  a0);            \
    a1 = fmaf(w0a.y, cw3,  a1); a0 = fmaf(w1a.y, cw4,  a0); a1 = fmaf(w2a.y, cw5,  a1);            \
    a0 = fmaf(w0a.z, cw6,  a0); a1 = fmaf(w1a.z, cw7,  a1); a0 = fmaf(w2a.z, cw8,  a0);            \
    a1 = fmaf(w0a.w, cw9,  a1); a0 = fmaf(w1a.w, cw10, a0); a1 = fmaf(w2a.w, cw11, a1);            \
    a0 = fmaf(w0b.x, cw12, a0); a1 = fmaf(w1b.x, cw13, a1); a0 = fmaf(w2b.x, cw14, a0);            \
    a1 = fmaf(w0b.y, cw15, a1); a0 = fmaf(w1b.y, cw16, a0); a1 = fmaf(w2b.y, cw17, a1);            \
    a0 = fmaf(w0b.z, cw18, a0); a1 = fmaf(w1b.z, cw19, a1); a0 = fmaf(w2b.z, cw20, a0);            \
    a1 = fmaf(w0b.w, cw21, a1); a0 = fmaf(w1b.w, cw22, a0); a1 = fmaf(w2b.w, cw23, a1);            \
    Y = fmaxf(a0 + a1, 0.f);                                                                       \
}while(0)

#define H1BCAST                                                                                    \
    const float hs0=rl(h1,0), hs1=rl(h1,1), hs2=rl(h1,2), hs3=rl(h1,3), hs4=rl(h1,4),              \
                hs5=rl(h1,5), hs6=rl(h1,6), hs7=rl(h1,7), hs8=rl(h1,8), hs9=rl(h1,9);

#define LAYER2 do{                                                                                 \
    float d0 = b2, d1 = 0.f;                                                                       \
    d0 = fmaf(hs0, wi2_0, d0);  d1 = fmaf(hs1, wi2_1, d1);                                         \
    d0 = fmaf(hs2, wi2_2, d0);  d1 = fmaf(hs3, wi2_3, d1);                                         \
    d0 = fmaf(hs4, wi2_4, d0);  d1 = fmaf(hs5, wi2_5, d1);                                         \
    d0 = fmaf(hs6, wi2_6, d0);  d1 = fmaf(hs7, wi2_7, d1);                                         \
    d0 = fmaf(hs8, wi2_8, d0);  d1 = fmaf(hs9, wi2_9, d1);                                         \
    d0 = fmaf(rl(h2,0), wh2_0, d0);  d1 = fmaf(rl(h2,1), wh2_1, d1);                               \
    d0 = fmaf(rl(h2,2), wh2_2, d0);  d1 = fmaf(rl(h2,3), wh2_3, d1);                               \
    d0 = fmaf(rl(h2,4), wh2_4, d0);  d1 = fmaf(rl(h2,5), wh2_5, d1);                               \
    d0 = fmaf(rl(h2,6), wh2_6, d0);  d1 = fmaf(rl(h2,7), wh2_7, d1);                               \
    d0 = fmaf(rl(h2,8), wh2_8, d0);  d1 = fmaf(rl(h2,9), wh2_9, d1);                               \
    const float g2  = d0 + d1;                                                                     \
    const float sg2 = sigf(g2 * zM);                                                               \
    const float act2 = fmaf(aA, sg2, aB);                                                          \
    const float ai2 = __shfl(act2, u,      64);                                                    \
    const float af2 = __shfl(act2, u + 10, 64);                                                    \
    const float ag2 = __shfl(act2, u + 20, 64);                                                    \
    const float ao2 = __shfl(act2, u + 30, 64);                                                    \
    c2 = fmaf(af2, c2, ai2 * ag2);                                                                 \
    h2 = ao2 * tanh_f(c2);                                                                         \
}while(0)

#define LAYER1(YV) do{                                                                             \
    float e0 = b1, e1 = 0.f;                                                                       \
    e0 = fmaf(rl(YV,0),  wi0,  e0);  e1 = fmaf(rl(YV,1),  wi1,  e1);                               \
    e0 = fmaf(rl(YV,2),  wi2,  e0);  e1 = fmaf(rl(YV,3),  wi3,  e1);                               \
    e0 = fmaf(rl(YV,4),  wi4,  e0);  e1 = fmaf(rl(YV,5),  wi5,  e1);                               \
    e0 = fmaf(rl(YV,6),  wi6,  e0);  e1 = fmaf(rl(YV,7),  wi7,  e1);                               \
    e0 = fmaf(rl(YV,8),  wi8,  e0);  e1 = fmaf(rl(YV,9),  wi9,  e1);                               \
    e0 = fmaf(rl(YV,10), wi10, e0);  e1 = fmaf(rl(YV,11), wi11, e1);                               \
    e0 = fmaf(rl(YV,12), wi12, e0);  e1 = fmaf(rl(YV,13), wi13, e1);                               \
    e0 = fmaf(rl(YV,14), wi14, e0);  e1 = fmaf(rl(YV,15), wi15, e1);                               \
    e0 = fmaf(hs0, wh1_0, e0);  e1 = fmaf(hs1, wh1_1, e1);                                         \
    e0 = fmaf(hs2, wh1_2, e0);  e1 = fmaf(hs3, wh1_3, e1);                                         \
    e0 = fmaf(hs4, wh1_4, e0);  e1 = fmaf(hs5, wh1_5, e1);                                         \
    e0 = fmaf(hs6, wh1_6, e0);  e1 = fmaf(hs7, wh1_7, e1);                                         \
    e0 = fmaf(hs8, wh1_8, e0);  e1 = fmaf(hs9, wh1_9, e1);                                         \
    const float g1  = e0 + e1;                                                                     \
    const float sg1 = sigf(g1 * zM);                                                               \
    const float act1 = fmaf(aA, sg1, aB);                                                          \
    const float ai1 = __shfl(act1, u,      64);                                                    \
    const float af1 = __shfl(act1, u + 10, 64);                                                    \
    const float ag1 = __shfl(act1, u + 20, 64);                                                    \
    const float ao1 = __shfl(act1, u + 30, 64);                                                    \
    c1 = fmaf(af1, c1, ai1 * ag1);                                                                 \
    h1n = ao1 * tanh_f(c1);                                                                        \
}while(0)

__global__ __launch_bounds__(64, 2)
void lstm_fused(const float* __restrict__ x,
                const float* __restrict__ conv_w, const float* __restrict__ conv_b,
                const float* __restrict__ w_ih1,  const float* __restrict__ w_hh1,
                const float* __restrict__ b_ih1,  const float* __restrict__ b_hh1,
                const float* __restrict__ w_ih2,  const float* __restrict__ w_hh2,
                const float* __restrict__ b_ih2,  const float* __restrict__ b_hh2,
                const float* __restrict__ lin_w,  const float* __restrict__ lin_b,
                float* __restrict__ out)
{
    const int lane  = threadIdx.x;
    const int batch = blockIdx.x;
    const int grow  = (lane < G4) ? lane : (G4-1);
    const int q     = grow / 10;
    const int u     = grow - q * 10;
    const int ch    = lane & 15;
    const bool isG  = (q == 2);
    float zM = isG ? 2.f : 1.f;      // tanh(z) = 2*sig(2z)-1
    float aA = isG ? 2.f : 1.f;
    float aB = isG ? -1.f : 0.f;
    PIN(zM); PIN(aA); PIN(aB);

    // ---- loop-invariant weights: named scalars, pinned into VGPRs ----
    const float* cwp = conv_w + ch*24;
    float cw0=cwp[0],  cw1=cwp[1],  cw2=cwp[2],  cw3=cwp[3],  cw4=cwp[4],  cw5=cwp[5];
    float cw6=cwp[6],  cw7=cwp[7],  cw8=cwp[8],  cw9=cwp[9],  cw10=cwp[10],cw11=cwp[11];
    float cw12=cwp[12],cw13=cwp[13],cw14=cwp[14],cw15=cwp[15],cw16=cwp[16],cw17=cwp[17];
    float cw18=cwp[18],cw19=cwp[19],cw20=cwp[20],cw21=cwp[21],cw22=cwp[22],cw23=cwp[23];
    PIN(cw0);PIN(cw1);PIN(cw2);PIN(cw3);PIN(cw4);PIN(cw5);PIN(cw6);PIN(cw7);
    PIN(cw8);PIN(cw9);PIN(cw10);PIN(cw11);PIN(cw12);PIN(cw13);PIN(cw14);PIN(cw15);
    PIN(cw16);PIN(cw17);PIN(cw18);PIN(cw19);PIN(cw20);PIN(cw21);PIN(cw22);PIN(cw23);
    float cb = conv_b[ch]; PIN(cb);

    const float* wip = w_ih1 + grow*CC;
    float wi0=wip[0],  wi1=wip[1],  wi2=wip[2],  wi3=wip[3];
    float wi4=wip[4],  wi5=wip[5],  wi6=wip[6],  wi7=wip[7];
    float wi8=wip[8],  wi9=wip[9],  wi10=wip[10],wi11=wip[11];
    float wi12=wip[12],wi13=wip[13],wi14=wip[14],wi15=wip[15];
    PIN(wi0);PIN(wi1);PIN(wi2);PIN(wi3);PIN(wi4);PIN(wi5);PIN(wi6);PIN(wi7);
    PIN(wi8);PIN(wi9);PIN(wi10);PIN(wi11);PIN(wi12);PIN(wi13);PIN(wi14);PIN(wi15);

    const float* p1 = w_hh1 + grow*HH;
    float wh1_0=p1[0],wh1_1=p1[1],wh1_2=p1[2],wh1_3=p1[3],wh1_4=p1[4];
    float wh1_5=p1[5],wh1_6=p1[6],wh1_7=p1[7],wh1_8=p1[8],wh1_9=p1[9];
    PIN(wh1_0);PIN(wh1_1);PIN(wh1_2);PIN(wh1_3);PIN(wh1_4);
    PIN(wh1_5);PIN(wh1_6);PIN(wh1_7);PIN(wh1_8);PIN(wh1_9);

    const float* p2 = w_ih2 + grow*HH;
    float wi2_0=p2[0],wi2_1=p2[1],wi2_2=p2[2],wi2_3=p2[3],wi2_4=p2[4];
    float wi2_5=p2[5],wi2_6=p2[6],wi2_7=p2[7],wi2_8=p2[8],wi2_9=p2[9];
    PIN(wi2_0);PIN(wi2_1);PIN(wi2_2);PIN(wi2_3);PIN(wi2_4);
    PIN(wi2_5);PIN(wi2_6);PIN(wi2_7);PIN(wi2_8);PIN(wi2_9);

    const float* p3 = w_hh2 + grow*HH;
    float wh2_0=p3[0],wh2_1=p3[1],wh2_2=p3[2],wh2_3=p3[3],wh2_4=p3[4];
    float wh2_5=p3[5],wh2_6=p3[6],wh2_7=p3[7],wh2_8=p3[8],wh2_9=p3[9];
    PIN(wh2_0);PIN(wh2_1);PIN(wh2_2);PIN(wh2_3);PIN(wh2_4);
    PIN(wh2_5);PIN(wh2_6);PIN(wh2_7);PIN(wh2_8);PIN(wh2_9);

    float b1 = b_ih1[grow] + b_hh1[grow]; PIN(b1);
    float b2 = b_ih2[grow] + b_hh2[grow]; PIN(b2);

    const float* xb = x + (size_t)batch * (TT*FF);

    float h1 = 0.f, c1 = 0.f, h2 = 0.f, c2 = 0.f, h1n;

    // sliding conv window rows t-1, t, t+1
    float4 w0a = make_float4(0.f,0.f,0.f,0.f), w0b = w0a;
    float4 w1a = *(const float4*)(xb + 0);
    float4 w1b = *(const float4*)(xb + 4);
    float4 w2a = *(const float4*)(xb + 8);
    float4 w2b = *(const float4*)(xb + 12);

    // ---- prologue: t=0, layer1 only ----
    {
        float y0; CONV_Y(y0);
        H1BCAST;                 // h1(-1)=0
        LAYER1(y0);
        h1 = h1n;
    }
    w0a = w1a; w0b = w1b; w1a = w2a; w1b = w2b;
    w2a = *(const float4*)(xb + 16);
    w2b = *(const float4*)(xb + 20);

    // ---- main loop: iteration t does layer2(t-1) || layer1(t) ----
    #pragma unroll 3
    for (int t = 1; t < TT; ++t){
        float4 nxa = make_float4(0.f,0.f,0.f,0.f), nxb = nxa;
        if (t + 2 < TT){
            const float* p = xb + (t+2)*FF;
            nxa = *(const float4*)p;
            nxb = *(const float4*)(p + 4);
        }
        float y; CONV_Y(y);
        {
            H1BCAST;             // h1(t-1) broadcasts, shared by both layers
            LAYER2;              // h2(t-1) — chain A
            LAYER1(y);           // h1(t)   — chain B
        }
        h1 = h1n;
        w0a = w1a; w0b = w1b; w1a = w2a; w1b = w2b; w2a = nxa; w2b = nxb;
    }
    // ---- epilogue: layer2 for t=TT-1 ----
    {
        H1BCAST;
        LAYER2;
    }

    // final: sigmoid(h2 . lin_w + lin_b); lanes 0..9 hold h2[0..9]
    float part = (lane < HH) ? h2 * lin_w[grow] : 0.f;
    #pragma unroll
    for (int off = 8; off > 0; off >>= 1) part += __shfl_xor(part, off, 16);
    if (lane == 0) out[batch] = sigf(part + lin_b[0]);
}

extern "C" void kernel_launch(void* const* d_in, const int* in_sizes, int n_in,
                              void* d_out, int out_size, void* d_ws, size_t ws_size,
                              hipStream_t stream) {
    const float* x      = (const float*)d_in[0];
    const float* conv_w = (const float*)d_in[1];
    const float* conv_b = (const float*)d_in[2];
    const float* w_ih1  = (const float*)d_in[3];
    const float* w_hh1  = (const float*)d_in[4];
    const float* b_ih1  = (const float*)d_in[5];
    const float* b_hh1  = (const float*)d_in[6];
    const float* w_ih2  = (const float*)d_in[7];
    const float* w_hh2  = (const float*)d_in[8];
    const float* b_ih2  = (const float*)d_in[9];
    const float* b_hh2  = (const float*)d_in[10];
    const float* lin_w  = (const float*)d_in[11];
    const float* lin_b  = (const float*)d_in[12];
    float* out = (float*)d_out;

    // one wave per batch: 2048 waves -> 2 per SIMD chip-wide
    lstm_fused<<<dim3(2048), dim3(64), 0, stream>>>(
        x, conv_w, conv_b, w_ih1, w_hh1, b_ih1, b_hh1,
        w_ih2, w_hh2, b_ih2, b_hh2, lin_w, lin_b, out);
}